// Round 1
// baseline (454.784 us; speedup 1.0000x reference)
//
#include <hip/hip_runtime.h>

// ---------------------------------------------------------------------------
// Motion_Grid: PE(sin/cos @ 3 freqs) -> 6 trilinear samples (3 grids) -> MLP
// ---------------------------------------------------------------------------

#define NPTS_BLK 256

// Pack grid + noise into (D,H,W,C) layout so one corner = one float4/float2.
template<int C>
__global__ __launch_bounds__(256)
void pack_grid_k(const float* __restrict__ g, const float* __restrict__ nz,
                 float* __restrict__ out, int nvox) {
    int v = blockIdx.x * 256 + threadIdx.x;
    if (v >= nvox) return;
    float vals[C];
#pragma unroll
    for (int c = 0; c < C; ++c) vals[c] = g[c * nvox + v] + nz[c * nvox + v];
#pragma unroll
    for (int c = 0; c < C; ++c) out[v * C + c] = vals[c];
}

// Trilinear sample with border-zero (valid-mask) semantics, channel-innermost vol.
template<int C, int S>
__device__ __forceinline__ void trilerp(const float* __restrict__ vol,
                                        float cx, float cy, float cz,
                                        float* __restrict__ f) {
    const float hs = (float)S * 0.5f;
    float x = fmaf(cx, hs, hs - 0.5f);
    float y = fmaf(cy, hs, hs - 0.5f);
    float z = fmaf(cz, hs, hs - 0.5f);
    float x0f = floorf(x), y0f = floorf(y), z0f = floorf(z);
    float tx = x - x0f, ty = y - y0f, tz = z - z0f;
    int x0 = (int)x0f, y0 = (int)y0f, z0 = (int)z0f;
    int x1 = x0 + 1, y1 = y0 + 1, z1 = z0 + 1;

    float wxs[2], wys[2], wzs[2];
    wxs[0] = (1.f - tx) * ((x0 >= 0 && x0 < S) ? 1.f : 0.f);
    wxs[1] = tx         * ((x1 >= 0 && x1 < S) ? 1.f : 0.f);
    wys[0] = (1.f - ty) * ((y0 >= 0 && y0 < S) ? 1.f : 0.f);
    wys[1] = ty         * ((y1 >= 0 && y1 < S) ? 1.f : 0.f);
    wzs[0] = (1.f - tz) * ((z0 >= 0 && z0 < S) ? 1.f : 0.f);
    wzs[1] = tz         * ((z1 >= 0 && z1 < S) ? 1.f : 0.f);

    int xs[2], ys[2], zs[2];
    xs[0] = min(max(x0, 0), S - 1) * C;
    xs[1] = min(max(x1, 0), S - 1) * C;
    ys[0] = min(max(y0, 0), S - 1);
    ys[1] = min(max(y1, 0), S - 1);
    zs[0] = min(max(z0, 0), S - 1);
    zs[1] = min(max(z1, 0), S - 1);

#pragma unroll
    for (int dz = 0; dz < 2; ++dz) {
#pragma unroll
        for (int dy = 0; dy < 2; ++dy) {
            const float wzy = wzs[dz] * wys[dy];
            const int rowoff = (zs[dz] * S + ys[dy]) * S * C;
#pragma unroll
            for (int dx = 0; dx < 2; ++dx) {
                const float w = wzy * wxs[dx];
                const float* p = vol + rowoff + xs[dx];
                if (C == 4) {
                    float4 v = *reinterpret_cast<const float4*>(p);
                    f[0] = fmaf(w, v.x, f[0]);
                    f[1] = fmaf(w, v.y, f[1]);
                    f[2] = fmaf(w, v.z, f[2]);
                    f[3] = fmaf(w, v.w, f[3]);
                } else {
                    float2 v = *reinterpret_cast<const float2*>(p);
                    f[0] = fmaf(w, v.x, f[0]);
                    f[1] = fmaf(w, v.y, f[1]);
                }
            }
        }
    }
}

__global__ __launch_bounds__(256)
void motion_grid_main(const float* __restrict__ x,
                      const float* __restrict__ g0,
                      const float* __restrict__ g1,
                      const float* __restrict__ g2,
                      const float* __restrict__ w1,
                      const float* __restrict__ b1,
                      const float* __restrict__ w2,
                      const float* __restrict__ b2,
                      float* __restrict__ out, int npts) {
    __shared__ float sW1[64 * 20];
    __shared__ float sB1[64];
    __shared__ float sW2[7 * 64];
    __shared__ float sB2[7];
    for (int i = threadIdx.x; i < 64 * 20; i += 256) sW1[i] = w1[i];
    for (int i = threadIdx.x; i < 7 * 64; i += 256) sW2[i] = w2[i];
    if (threadIdx.x < 64) sB1[threadIdx.x] = b1[threadIdx.x];
    if (threadIdx.x < 7) sB2[threadIdx.x] = b2[threadIdx.x];
    __syncthreads();

    const int p = blockIdx.x * 256 + threadIdx.x;
    if (p >= npts) return;

    const float xv0 = x[p * 3 + 0];
    const float xv1 = x[p * 3 + 1];
    const float xv2 = x[p * 3 + 2];

    // v_sin/v_cos take revolutions: sin(pi*x) = sin_hw(0.5x), sin(2pi*x) = sin_hw(x),
    // sin(4pi*x) = sin_hw(2x). x in [0,1) so no range reduction needed.
    float s1[3], c1[3], s2[3], c2[3], s4[3], c4[3];
    {
        const float xs[3] = {xv0, xv1, xv2};
#pragma unroll
        for (int d = 0; d < 3; ++d) {
            s1[d] = __builtin_amdgcn_sinf(0.5f * xs[d]);
            c1[d] = __builtin_amdgcn_cosf(0.5f * xs[d]);
            s2[d] = __builtin_amdgcn_sinf(xs[d]);
            c2[d] = __builtin_amdgcn_cosf(xs[d]);
            s4[d] = __builtin_amdgcn_sinf(2.0f * xs[d]);
            c4[d] = __builtin_amdgcn_cosf(2.0f * xs[d]);
        }
    }

    // Feature vector, order must match jnp.concatenate(feats, axis=0):
    // [lvl0 sin (4ch), lvl0 cos (4ch), lvl1 sin (4ch), lvl1 cos (4ch),
    //  lvl2 sin (2ch), lvl2 cos (2ch)]
    float f[20];
#pragma unroll
    for (int i = 0; i < 20; ++i) f[i] = 0.f;

    trilerp<4, 32>(g0, s1[0], s1[1], s1[2], f + 0);
    trilerp<4, 32>(g0, c1[0], c1[1], c1[2], f + 4);
    trilerp<4, 64>(g1, s2[0], s2[1], s2[2], f + 8);
    trilerp<4, 64>(g1, c2[0], c2[1], c2[2], f + 12);
    trilerp<2, 128>(g2, s4[0], s4[1], s4[2], f + 16);
    trilerp<2, 128>(g2, c4[0], c4[1], c4[2], f + 18);

    // MLP: h = leaky_relu(f @ w1^T + b1); out = h @ w2^T + b2
    float acc[7];
#pragma unroll
    for (int o = 0; o < 7; ++o) acc[o] = sB2[o];

#pragma unroll 4
    for (int j = 0; j < 64; ++j) {
        float s = sB1[j];
#pragma unroll
        for (int k = 0; k < 20; ++k) s = fmaf(f[k], sW1[j * 20 + k], s);
        float h = fmaxf(s, 0.01f * s);  // leaky_relu (monotone max form)
#pragma unroll
        for (int o = 0; o < 7; ++o) acc[o] = fmaf(h, sW2[o * 64 + j], acc[o]);
    }

#pragma unroll
    for (int o = 0; o < 7; ++o) out[p * 7 + o] = acc[o];
}

extern "C" void kernel_launch(void* const* d_in, const int* in_sizes, int n_in,
                              void* d_out, int out_size, void* d_ws, size_t ws_size,
                              hipStream_t stream) {
    const float* x  = (const float*)d_in[0];
    const float* g0 = (const float*)d_in[1];
    const float* g1 = (const float*)d_in[2];
    const float* g2 = (const float*)d_in[3];
    const float* n0 = (const float*)d_in[4];
    const float* n1 = (const float*)d_in[5];
    const float* n2 = (const float*)d_in[6];
    const float* w1 = (const float*)d_in[7];
    const float* b1 = (const float*)d_in[8];
    const float* w2 = (const float*)d_in[9];
    const float* b2 = (const float*)d_in[10];
    float* out = (float*)d_out;

    char* ws = (char*)d_ws;
    float* p0 = (float*)(ws);                          // 32^3 * 4 ch = 512 KiB
    float* p1 = (float*)(ws + 524288);                 // 64^3 * 4 ch = 4 MiB
    float* p2 = (float*)(ws + 524288 + 4194304);       // 128^3 * 2 ch = 16 MiB

    const int npts = in_sizes[0] / 3;

    pack_grid_k<4><<<(32768 + 255) / 256, 256, 0, stream>>>(g0, n0, p0, 32768);
    pack_grid_k<4><<<(262144 + 255) / 256, 256, 0, stream>>>(g1, n1, p1, 262144);
    pack_grid_k<2><<<(2097152 + 255) / 256, 256, 0, stream>>>(g2, n2, p2, 2097152);

    motion_grid_main<<<(npts + 255) / 256, 256, 0, stream>>>(
        x, p0, p1, p2, w1, b1, w2, b2, out, npts);
}